// Round 10
// baseline (4330.572 us; speedup 1.0000x reference)
//
#include <hip/hip_runtime.h>

#define B_ 4
#define N_ 4096
#define K_ 16
#define C_ 128
#define NQ (B_*N_)            // 16384 query points
#define COLS_TOT (NQ*K_)      // 262144 (b,n,k) columns
#define CNT_F 262144.0f
#define EPS_ 1e-5f

typedef __attribute__((ext_vector_type(4))) float f4;

__device__ __forceinline__ unsigned short f2bf(float f){
  unsigned u = __builtin_bit_cast(unsigned, f);
  u = u + 0x7fffu + ((u >> 16) & 1u);     // RNE
  return (unsigned short)(u >> 16);
}
__device__ __forceinline__ float bf2f(unsigned short h){
  return __builtin_bit_cast(float, ((unsigned)h) << 16);
}

// ---------------------------------------------------------------------------
// Brute-force exact top-16, sgemm-mirror fp32 arithmetic:
//   sq  = rn(rn(rn(x*x)+rn(y*y))+rn(z*z))              (XLA/np reduce, plain)
//   dot = fma(z1,z2, fma(y1,y2, rn(x1*x2)))            (BLAS k-ascending FMA)
//   d   = rn(rn(sq1+sq2) - 2*dot)                      (2*dot exact)
// Low-index stable ties (lax.top_k convention).
// Block: 256 thr = 64 queries x 4 candidate-parts. Grid: 256 (b x 64 qgrps).
// ---------------------------------------------------------------------------
__global__ __launch_bounds__(256) void knn_brute(
    const float* __restrict__ pos1, const float* __restrict__ pos2,
    int* __restrict__ idxout)
{
  __shared__ __align__(16) float pts[4096*4];      // 64 KB
  __shared__ float pD[64][4];
  __shared__ int   pM[64][4];
  int t = threadIdx.x;
  int bx = blockIdx.x;
  int b = bx >> 6, qgrp = bx & 63;
  const float* p2 = pos2 + (size_t)b*3*N_;
  for (int i = 0; i < 16; ++i){
    int m = i*256 + t;
    float x = p2[m], y = p2[N_ + m], z = p2[2*N_ + m];
    float sq = __fadd_rn(__fadd_rn(__fmul_rn(x,x), __fmul_rn(y,y)), __fmul_rn(z,z));
    f4 v; v.x = x; v.y = y; v.z = z; v.w = sq;
    *(f4*)(pts + m*4) = v;
  }
  __syncthreads();

  int ql = t & 63, part = t >> 6;
  int n = qgrp*64 + ql;
  const float* p1 = pos1 + (size_t)b*3*N_;
  float qx = p1[n], qy = p1[N_ + n], qz = p1[2*N_ + n];
  float qs = __fadd_rn(__fadd_rn(__fmul_rn(qx,qx), __fmul_rn(qy,qy)), __fmul_rn(qz,qz));
  int q = b*N_ + n;

  float dprev = -3.4e38f; int mprev = -1;
  int m0 = part*1024;
  for (int s = 0; s < 16; ++s){
    float best = 3.4e38f; int bestm = 1 << 30;
    for (int mm = 0; mm < 1024; ++mm){
      int m = m0 + mm;
      f4 c = *(const f4*)(pts + m*4);
      // sgemm k-ascending FMA accumulation
      float dot = __builtin_fmaf(qz, c.z,
                    __builtin_fmaf(qy, c.y, __fmul_rn(qx, c.x)));
      float d = __fsub_rn(__fadd_rn(qs, c.w), __fmul_rn(2.0f, dot));
      bool gt_prev = (d > dprev) || (d == dprev && m > mprev);
      bool lt_best = (d < best)  || (d == best  && m < bestm);
      if (gt_prev && lt_best){ best = d; bestm = m; }
    }
    pD[ql][part] = best; pM[ql][part] = bestm;
    __syncthreads();
    float fb = 3.4e38f; int fm = 1 << 30;
    #pragma unroll
    for (int w = 0; w < 4; ++w){
      float dw = pD[ql][w]; int mw = pM[ql][w];
      bool lt = (dw < fb) || (dw == fb && mw < fm);
      if (lt){ fb = dw; fm = mw; }
    }
    if (part == 0) idxout[(size_t)q*16 + s] = fm;
    dprev = fb; mprev = fm;
    __syncthreads();
  }
}

// ---------------------------------------------------------------------------
// SIMPLE fp32 layer 0 (r5): y0 = W0 . [pos_diff; feat2_g; feat1]
// ---------------------------------------------------------------------------
__global__ __launch_bounds__(256) void conv0_simple(
    const float* __restrict__ pos1, const float* __restrict__ pos2,
    const float* __restrict__ feat1, const float* __restrict__ feat2,
    const float* __restrict__ W0, const int* __restrict__ idx,
    unsigned short* __restrict__ ybuf)
{
  __shared__ float X0[32][261];
  int t = threadIdx.x;
  int col0 = blockIdx.x * 32;
  int cs = t & 31, cpart = t >> 5;
  {
    int col = col0 + cs;
    int nabs = col >> 4;
    int b = nabs >> 12, n = nabs & 4095;
    int m = idx[col];
    for (int c = cpart; c < 259; c += 8){
      float v;
      if (c < 3)        v = pos2[(size_t)(b*3+c)*N_ + m] - pos1[(size_t)(b*3+c)*N_ + n];
      else if (c < 131) v = feat2[((size_t)b*C_ + (c-3))*N_ + m];
      else              v = feat1[((size_t)b*C_ + (c-131))*N_ + n];
      X0[cs][c] = v;
    }
  }
  __syncthreads();
  int lane = t & 63, w = t >> 6;
  int colw = lane & 31, chalf = lane >> 5;
  int cbase = chalf * 130;
  int cnt = 130 - chalf;
  unsigned short* dst = ybuf + (size_t)(col0 + colw)*C_;
  for (int oo = 0; oo < 32; ++oo){
    int o = oo*4 + w;
    const float* wr = W0 + (size_t)o*259 + cbase;
    float acc = 0.f;
    for (int cc = 0; cc < cnt; ++cc)
      acc = fmaf(wr[cc], X0[colw][cbase + cc], acc);
    acc += __shfl_xor(acc, 32);
    if (chalf == 0) dst[o] = f2bf(acc);
  }
}

// ---------------------------------------------------------------------------
// SIMPLE fp32 layers 1/2 (r5)
// ---------------------------------------------------------------------------
__global__ __launch_bounds__(256) void conv12_simple(
    unsigned short* ybuf, const float* __restrict__ W,
    const float* __restrict__ cA, const float* __restrict__ cB)
{
  __shared__ float X[32][129];
  int t = threadIdx.x;
  int col0 = blockIdx.x * 32;
  int cs = t & 31, cpart = t >> 5;
  {
    const unsigned short* src = ybuf + (size_t)(col0 + cs)*C_;
    for (int c = cpart; c < 128; c += 8){
      float v = fmaf(bf2f(src[c]), cA[c], cB[c]);
      X[cs][c] = v > 0.f ? v : 0.f;
    }
  }
  __syncthreads();
  int lane = t & 63, w = t >> 6;
  int colw = lane & 31, chalf = lane >> 5;
  int cbase = chalf * 64;
  unsigned short* dst = ybuf + (size_t)(col0 + colw)*C_;
  for (int oo = 0; oo < 32; ++oo){
    int o = oo*4 + w;
    const float* wr = W + (size_t)o*C_ + cbase;
    float acc = 0.f;
    #pragma unroll
    for (int cc = 0; cc < 64; ++cc)
      acc = fmaf(wr[cc], X[colw][cbase + cc], acc);
    acc += __shfl_xor(acc, 32);
    if (chalf == 0) dst[o] = f2bf(acc);
  }
}

__global__ __launch_bounds__(256) void stats_simple(
    const unsigned short* __restrict__ ybuf, float* __restrict__ partialsS)
{
  int t = threadIdx.x;
  int ch = t & 127, sub = t >> 7;
  int base = blockIdx.x*512 + sub*256;
  float s1 = 0.f, s2 = 0.f;
  for (int cc = 0; cc < 256; ++cc){
    float v = bf2f(ybuf[(size_t)(base + cc)*C_ + ch]);
    s1 += v; s2 = fmaf(v, v, s2);
  }
  partialsS[(size_t)blockIdx.x*512 + t]       = s1;
  partialsS[(size_t)blockIdx.x*512 + 256 + t] = s2;
}

__global__ __launch_bounds__(256) void finalize_simple(
    const float* __restrict__ P,
    const float* __restrict__ g, const float* __restrict__ bb,
    float* __restrict__ cA, float* __restrict__ cB)
{
  int t = threadIdx.x;
  if (t < 128){
    float s1 = 0.f, s2 = 0.f;
    for (int r = 0; r < 512; ++r){
      const float* row = P + (size_t)r*512;
      s1 += row[t] + row[128 + t];
      s2 += row[256 + t] + row[384 + t];
    }
    float mu = s1 / CNT_F;
    float var = s2 / CNT_F - mu*mu;
    float A = g[t] * rsqrtf(var + EPS_);
    cA[t] = A; cB[t] = bb[t] - mu*A;
  }
}

__global__ __launch_bounds__(256) void max_simple(
    const unsigned short* __restrict__ ybuf, float* __restrict__ y2max)
{
  int t = threadIdx.x;
  int nabs = blockIdx.x*2 + (t >> 7);
  int ch = t & 127;
  const unsigned short* src = ybuf + (size_t)nabs*16*C_ + ch;
  float m = bf2f(src[0]);
  #pragma unroll
  for (int k = 1; k < 16; ++k) m = fmaxf(m, bf2f(src[(size_t)k*C_]));
  y2max[(size_t)nabs*C_ + ch] = m;
}

__global__ __launch_bounds__(256) void k7_out(
    const float* __restrict__ y2max, const float* __restrict__ cA,
    const float* __restrict__ cB, float* __restrict__ outF)
{
  __shared__ __align__(16) float T[128*65];
  int t = threadIdx.x, bid = blockIdx.x;
  int b = bid >> 6, n0 = (bid & 63)*64;
  {
    int nl = t >> 2, o0 = (t & 3)*32;
    const float* src = y2max + ((size_t)b*N_ + n0 + nl)*C_ + o0;
    #pragma unroll
    for (int jj = 0; jj < 8; ++jj){
      f4 v = *(const f4*)(src + jj*4);
      T[(o0 + jj*4 + 0)*65 + nl] = v.x;
      T[(o0 + jj*4 + 1)*65 + nl] = v.y;
      T[(o0 + jj*4 + 2)*65 + nl] = v.z;
      T[(o0 + jj*4 + 3)*65 + nl] = v.w;
    }
  }
  __syncthreads();
  {
    int o = t >> 1, half = t & 1;
    float A = cA[o], Bb = cB[o];
    float* dst = outF + ((size_t)b*C_ + o)*N_ + n0 + half*32;
    #pragma unroll
    for (int jj = 0; jj < 8; ++jj){
      f4 v;
      float x0 = fmaf(T[o*65 + half*32 + jj*4+0], A, Bb);
      float x1 = fmaf(T[o*65 + half*32 + jj*4+1], A, Bb);
      float x2 = fmaf(T[o*65 + half*32 + jj*4+2], A, Bb);
      float x3 = fmaf(T[o*65 + half*32 + jj*4+3], A, Bb);
      v.x = x0 > 0.f ? x0 : 0.f; v.y = x1 > 0.f ? x1 : 0.f;
      v.z = x2 > 0.f ? x2 : 0.f; v.w = x3 > 0.f ? x3 : 0.f;
      *(f4*)(dst + jj*4) = v;
    }
  }
}

// ---------------------------------------------------------------------------
extern "C" void kernel_launch(void* const* d_in, const int* in_sizes, int n_in,
                              void* d_out, int out_size, void* d_ws, size_t ws_size,
                              hipStream_t stream)
{
  (void)in_sizes; (void)n_in; (void)out_size; (void)ws_size;
  const float* pos1  = (const float*)d_in[0];
  const float* pos2  = (const float*)d_in[1];
  const float* feat1 = (const float*)d_in[2];
  const float* feat2 = (const float*)d_in[3];
  const float* W0 = (const float*)d_in[4];
  const float* W1 = (const float*)d_in[5];
  const float* W2 = (const float*)d_in[6];
  const float* g0 = (const float*)d_in[7];
  const float* g1 = (const float*)d_in[8];
  const float* g2 = (const float*)d_in[9];
  const float* b0 = (const float*)d_in[10];
  const float* b1 = (const float*)d_in[11];
  const float* b2 = (const float*)d_in[12];

  char* ws = (char*)d_ws;
  size_t off = 0;
  auto alloc = [&](size_t bytes){ size_t r = off; off += (bytes + 255) & ~(size_t)255; return r; };
  int*   idx      = (int*)  (ws + alloc((size_t)COLS_TOT*4));
  unsigned short* ybuf = (unsigned short*)(ws + alloc((size_t)COLS_TOT*C_*2));
  float* y2max    = (float*)(ws + alloc((size_t)NQ*C_*4));
  float* partialsS= (float*)(ws + alloc((size_t)512*512*4));
  float* coef     = (float*)(ws + alloc((size_t)6*128*4));

  float* cA0 = coef,       *cB0 = coef + 128;
  float* cA1 = coef + 256, *cB1 = coef + 384;
  float* cA2 = coef + 512, *cB2 = coef + 640;
  float* out1 = (float*)d_out + (size_t)B_*3*N_;

  knn_brute<<<256, 256, 0, stream>>>(pos1, pos2, idx);

  conv0_simple<<<COLS_TOT/32, 256, 0, stream>>>(pos1, pos2, feat1, feat2, W0, idx, ybuf);
  stats_simple<<<512, 256, 0, stream>>>(ybuf, partialsS);
  finalize_simple<<<1, 256, 0, stream>>>(partialsS, g0, b0, cA0, cB0);

  conv12_simple<<<COLS_TOT/32, 256, 0, stream>>>(ybuf, W1, cA0, cB0);
  stats_simple<<<512, 256, 0, stream>>>(ybuf, partialsS);
  finalize_simple<<<1, 256, 0, stream>>>(partialsS, g1, b1, cA1, cB1);

  conv12_simple<<<COLS_TOT/32, 256, 0, stream>>>(ybuf, W2, cA1, cB1);
  stats_simple<<<512, 256, 0, stream>>>(ybuf, partialsS);
  finalize_simple<<<1, 256, 0, stream>>>(partialsS, g2, b2, cA2, cB2);

  max_simple<<<NQ/2, 256, 0, stream>>>(ybuf, y2max);
  k7_out<<<256, 256, 0, stream>>>(y2max, cA2, cB2, out1);
  hipMemcpyAsync(d_out, d_in[0], (size_t)B_*3*N_*4, hipMemcpyDeviceToDevice, stream);
}

// Round 11
// 414.264 us; speedup vs baseline: 10.4537x; 10.4537x over previous
//
#include <hip/hip_runtime.h>

#define B_ 4
#define N_ 4096
#define K_ 16
#define C_ 128
#define NQ (B_*N_)            // 16384 query points
#define COLS_TOT (NQ*K_)      // 262144 (b,n,k) columns
#define CNT_F 262144.0f
#define EPS_ 1e-5f

typedef __attribute__((ext_vector_type(8))) short short8;
typedef __attribute__((ext_vector_type(4))) float f4;
typedef __attribute__((ext_vector_type(4))) int i4;

__device__ __forceinline__ unsigned short f2bf(float f){
  unsigned u = __builtin_bit_cast(unsigned, f);
  u = u + 0x7fffu + ((u >> 16) & 1u);     // RNE
  return (unsigned short)(u >> 16);
}
__device__ __forceinline__ float bf2f(unsigned short h){
  return __builtin_bit_cast(float, ((unsigned)h) << 16);
}
// LDS column swizzle: XOR low3 col bits with bits 3..5 -> spreads bank groups
__device__ __forceinline__ int swzc(int c){ return c ^ ((c >> 3) & 7); }

// ---------------------------------------------------------------------------
// Weight conversion: W0b=W0[:,3:131], W0c=W0[:,131:259], W1, W2 -> bf16
// ---------------------------------------------------------------------------
__global__ __launch_bounds__(256) void wconv(
    const float* __restrict__ W0, const float* __restrict__ W1, const float* __restrict__ W2,
    unsigned short* __restrict__ W0b, unsigned short* __restrict__ W0c,
    unsigned short* __restrict__ W1b, unsigned short* __restrict__ W2b)
{
  int i = blockIdx.x * 256 + threadIdx.x;     // 0..65535
  int sel = i >> 14, r = i & 16383;
  int o = r >> 7, c = r & 127;
  float v; unsigned short* dst;
  if (sel == 0)      { v = W0[o*259 + 3   + c]; dst = W0b; }
  else if (sel == 1) { v = W0[o*259 + 131 + c]; dst = W0c; }
  else if (sel == 2) { v = W1[o*128 + c];       dst = W1b; }
  else               { v = W2[o*128 + c];       dst = W2b; }
  dst[r] = f2bf(v);
}

// ---------------------------------------------------------------------------
// KNN stage 1 — sgemm-mirror fp32 arithmetic (VERIFIED r10):
//   sq  = rn(rn(rn(x*x)+rn(y*y))+rn(z*z))
//   dot = fma(z1,z2, fma(y1,y2, rn(x1*x2)))      (BLAS k-ascending FMA)
//   d   = rn(rn(sq1+sq2) - 2*dot)
// Chunked top-16 with pending buffer; low-index stable ties.
// ---------------------------------------------------------------------------
__global__ __launch_bounds__(256) void knn_chunk(
    const float* __restrict__ pos1, const float* __restrict__ pos2,
    float* __restrict__ kdout, int* __restrict__ kiout)
{
  __shared__ __align__(16) float pts[1024*4];   // 16 KB
  int bx = blockIdx.x;
  int b = bx >> 6, rest = bx & 63, ngrp = rest >> 2, chunk = rest & 3;
  int t = threadIdx.x;
  int m0 = chunk * 1024;
  const float* p2 = pos2 + (size_t)b*3*N_;
  for (int i = 0; i < 4; ++i){
    int m = m0 + i*256 + t;
    float x = p2[m], y = p2[N_ + m], z = p2[2*N_ + m];
    float sq = __fadd_rn(__fadd_rn(__fmul_rn(x,x), __fmul_rn(y,y)), __fmul_rn(z,z));
    f4 v; v.x = x; v.y = y; v.z = z; v.w = sq;
    *(f4*)(pts + (i*256 + t)*4) = v;
  }
  __syncthreads();

  int n = ngrp*256 + t;
  const float* p1 = pos1 + (size_t)b*3*N_;
  float qx = p1[n], qy = p1[N_ + n], qz = p1[2*N_ + n];
  float qs = __fadd_rn(__fadd_rn(__fmul_rn(qx,qx), __fmul_rn(qy,qy)), __fmul_rn(qz,qz));

  float kd[16]; int ki[16];
  #pragma unroll
  for (int j = 0; j < 16; ++j){ kd[j] = 3.4e38f; ki[j] = 0; }
  float worst = 3.4e38f;
  float pd = 0.f; int pi = 0; bool pv = false;

  auto flush = [&](){
    float d0 = pv ? pd : 3.4e38f; int i0 = pi;
    #pragma unroll
    for (int j = 15; j >= 1; --j){
      bool cj = kd[j] > d0, cm = kd[j-1] > d0;
      kd[j] = cj ? (cm ? kd[j-1] : d0) : kd[j];
      ki[j] = cj ? (cm ? ki[j-1] : i0) : ki[j];
    }
    { bool c0 = kd[0] > d0; kd[0] = c0 ? d0 : kd[0]; ki[0] = c0 ? i0 : ki[0]; }
    worst = kd[15]; pv = false;
  };

  for (int it = 0; it < 1024; ++it){
    f4 c = *(const f4*)(pts + it*4);
    float dot = __builtin_fmaf(qz, c.z,
                  __builtin_fmaf(qy, c.y, __fmul_rn(qx, c.x)));
    float d = __fsub_rn(__fadd_rn(qs, c.w), __fmul_rn(2.0f, dot));
    bool pass = d < worst;
    if (__any(pass && pv)) flush();       // overflow flush
    if (pass){ pd = d; pi = m0 + it; pv = true; }
    if ((it & 7) == 7){ if (__any(pv)) flush(); }
  }
  if (__any(pv)) flush();

  int q = b*N_ + n;
  #pragma unroll
  for (int j = 0; j < 16; ++j){
    kdout[(size_t)q*64 + chunk*16 + j] = kd[j];
    kiout[(size_t)q*64 + chunk*16 + j] = ki[j];
  }
}

// KNN stage 2: merge 4 sorted 16-lists (stable low-index: chunks in order)
__global__ __launch_bounds__(256) void knn_merge(
    const float* __restrict__ kdin, const int* __restrict__ kiin, int* __restrict__ idxout)
{
  int q = blockIdx.x*256 + threadIdx.x;
  float kd[16]; int ki[16];
  #pragma unroll
  for (int j = 0; j < 16; ++j){ kd[j] = 3.4e38f; ki[j] = 0; }
  const float* dsrc = kdin + (size_t)q*64;
  const int*   isrc = kiin + (size_t)q*64;
  for (int s4 = 0; s4 < 16; ++s4){
    f4 dv = *(const f4*)(dsrc + s4*4);
    i4 iv = *(const i4*)(isrc + s4*4);
    #pragma unroll
    for (int e = 0; e < 4; ++e){
      float d0 = dv[e]; int i0 = iv[e];
      #pragma unroll
      for (int j = 15; j >= 1; --j){
        bool cj = kd[j] > d0, cm = kd[j-1] > d0;
        kd[j] = cj ? (cm ? kd[j-1] : d0) : kd[j];
        ki[j] = cj ? (cm ? ki[j-1] : i0) : ki[j];
      }
      { bool c0 = kd[0] > d0; kd[0] = c0 ? d0 : kd[0]; ki[0] = c0 ? i0 : ki[0]; }
    }
  }
  #pragma unroll
  for (int j = 0; j < 16; ++j) idxout[(size_t)q*16 + j] = ki[j];
}

// ---------------------------------------------------------------------------
// P1: F2t[b][m][o] = (W0b @ feature2), PREt[b][n][o] = (W0c @ feature1)
// MFMA GEMM, 128 out-ch x 128 cols per block, K=128.
// ---------------------------------------------------------------------------
__global__ __launch_bounds__(256) void p1_gemm(
    const float* __restrict__ feat2, const float* __restrict__ feat1,
    const unsigned short* __restrict__ W0b, const unsigned short* __restrict__ W0c,
    float* __restrict__ F2t, float* __restrict__ PREt)
{
  __shared__ __align__(16) unsigned short X[16*128*8];  // [kb][col(swz)][8] 32KB
  int bid = blockIdx.x;
  int sel = bid >> 7;
  const float* src = sel ? feat1 : feat2;
  const unsigned short* W = sel ? W0c : W0b;
  float* dst = sel ? PREt : F2t;
  int c0 = (bid & 127) * 128;
  int b = c0 >> 12, mm0 = c0 & 4095;
  int t = threadIdx.x;
  {
    int ch = t >> 1, half = t & 1;
    const float* s = src + ((size_t)b*C_ + ch)*N_ + mm0 + half*64;
    int kb = ch >> 3, e = ch & 7;
    for (int mi = 0; mi < 64; ++mi){
      int col = half*64 + mi;
      X[kb*1024 + swzc(col)*8 + e] = f2bf(s[mi]);
    }
  }
  int lane = t & 63, w = t >> 6;
  int or0 = (w >> 1)*64, c0w = (w & 1)*64;
  int lr = lane & 15, lg = lane >> 4;
  short8 af[4][4];
  #pragma unroll
  for (int ks = 0; ks < 4; ++ks)
    #pragma unroll
    for (int i = 0; i < 4; ++i)
      af[ks][i] = *(const short8*)(W + (or0 + 16*i + lr)*128 + ks*32 + 8*lg);
  __syncthreads();

  f4 acc[4][4] = {};
  #pragma unroll
  for (int ks = 0; ks < 4; ++ks){
    short8 bfr[4];
    #pragma unroll
    for (int j = 0; j < 4; ++j)
      bfr[j] = *(const short8*)(X + (ks*4 + lg)*1024 + swzc(c0w + 16*j + lr)*8);
    #pragma unroll
    for (int i = 0; i < 4; ++i)
      #pragma unroll
      for (int j = 0; j < 4; ++j)
        acc[i][j] = __builtin_amdgcn_mfma_f32_16x16x32_bf16(af[ks][i], bfr[j], acc[i][j], 0, 0, 0);
  }
  #pragma unroll
  for (int i = 0; i < 4; ++i)
    #pragma unroll
    for (int j = 0; j < 4; ++j){
      int col = c0 + c0w + 16*j + lr;
      *(f4*)(dst + (size_t)col*C_ + or0 + 16*i + 4*lg) = acc[i][j];
    }
}

// ---------------------------------------------------------------------------
// K3: y0[col][o] = F2t[b][m][o] + PREt[b][n][o] + W0a . pos_diff  (raw, pre-BN)
// Writes bf16 ybuf, per-block channel sum/sumsq partials.
// ---------------------------------------------------------------------------
__global__ __launch_bounds__(256) void k3_y0(
    const float* __restrict__ pos1, const float* __restrict__ pos2,
    const float* __restrict__ W0, const int* __restrict__ idx,
    const float* __restrict__ F2t, const float* __restrict__ PREt,
    unsigned short* __restrict__ ybuf, float* __restrict__ partials)
{
  __shared__ float w0a[384];
  __shared__ float ldsS[256];
  int t = threadIdx.x;
  for (int i = t; i < 384; i += 256) w0a[i] = W0[(i/3)*259 + (i%3)];
  __syncthreads();
  int cloc = t & 15, chg = t >> 4, ch0 = chg*8;
  float wx[8], wy[8], wz[8];
  #pragma unroll
  for (int e = 0; e < 8; ++e){
    wx[e] = w0a[(ch0+e)*3]; wy[e] = w0a[(ch0+e)*3+1]; wz[e] = w0a[(ch0+e)*3+2];
  }
  float s1[8] = {}, s2[8] = {};
  int base = blockIdx.x * 256;
  for (int it = 0; it < 16; ++it){
    int col = base + it*16 + cloc;
    int nabs = col >> 4;
    int b = nabs >> 12, n = nabs & 4095;
    int m = idx[col];
    float dx = pos2[(size_t)(b*3+0)*N_ + m] - pos1[(size_t)(b*3+0)*N_ + n];
    float dy = pos2[(size_t)(b*3+1)*N_ + m] - pos1[(size_t)(b*3+1)*N_ + n];
    float dz = pos2[(size_t)(b*3+2)*N_ + m] - pos1[(size_t)(b*3+2)*N_ + n];
    const float* f2 = F2t  + ((size_t)b*N_ + m)*C_ + ch0;
    const float* pr = PREt + ((size_t)b*N_ + n)*C_ + ch0;
    short8 sv;
    #pragma unroll
    for (int e = 0; e < 8; ++e){
      float y = f2[e] + pr[e];
      y = fmaf(wx[e], dx, y); y = fmaf(wy[e], dy, y); y = fmaf(wz[e], dz, y);
      s1[e] += y; s2[e] = fmaf(y, y, s2[e]);
      sv[e] = (short)f2bf(y);
    }
    *(short8*)(ybuf + (size_t)col*C_ + ch0) = sv;
  }
  #pragma unroll
  for (int e = 0; e < 8; ++e){
    float a = s1[e], q = s2[e];
    #pragma unroll
    for (int sft = 1; sft < 16; sft <<= 1){ a += __shfl_xor(a, sft); q += __shfl_xor(q, sft); }
    if (cloc == 0){ ldsS[ch0 + e] = a; ldsS[128 + ch0 + e] = q; }
  }
  __syncthreads();
  partials[(size_t)blockIdx.x*256 + t] = ldsS[t];
}

// ---------------------------------------------------------------------------
// Stats reduction (deterministic, 2 stages) + BN coef
// ---------------------------------------------------------------------------
__global__ __launch_bounds__(256) void reduce1(const float* __restrict__ partials,
                                               float* __restrict__ partial2)
{
  int t = threadIdx.x, r0 = blockIdx.x*32;
  float a = 0.f;
  #pragma unroll 4
  for (int i = 0; i < 32; ++i) a += partials[(size_t)(r0+i)*256 + t];
  partial2[(size_t)blockIdx.x*256 + t] = a;
}

__global__ __launch_bounds__(256) void finalize(const float* __restrict__ partial2, int rows,
    const float* __restrict__ g, const float* __restrict__ bb,
    float* __restrict__ cA, float* __restrict__ cB)
{
  __shared__ float sh[256];
  int t = threadIdx.x;
  float a = 0.f;
  for (int i = 0; i < rows; ++i) a += partial2[(size_t)i*256 + t];
  sh[t] = a;
  __syncthreads();
  if (t < 128){
    float mu = sh[t] / CNT_F;
    float var = sh[128 + t] / CNT_F - mu*mu;
    float A = g[t] * rsqrtf(var + EPS_);
    cA[t] = A; cB[t] = bb[t] - mu*A;
  }
}

// ---------------------------------------------------------------------------
// Layer GEMM: x = relu(A*y_in+B) (bf16), y_out = W @ x. In-place on ybuf.
// LAST=1: max-reduce over K in-register (BN monotone: A=g/sigma>0), store y2max.
// ---------------------------------------------------------------------------
template<int LAST>
__global__ __launch_bounds__(256,2) void layer_gemm(
    unsigned short* ybuf,                        // in/out (aliased on purpose)
    const unsigned short* __restrict__ Wbf,
    const float* __restrict__ cA, const float* __restrict__ cB,
    float* __restrict__ y2max,
    float* __restrict__ partials)
{
  __shared__ __align__(16) char lds[38912];
  unsigned short* X = (unsigned short*)lds;      // [16 kb][128 col(swz)][8]  32KB
  float* ldsA = (float*)(lds + 34816);
  float* ldsB = ldsA + 128;
  float* ldsS = ldsB + 128;                      // [2][256]
  int t = threadIdx.x;
  int c0 = blockIdx.x * 128;
  if (t < 128){ ldsA[t] = cA[t]; ldsB[t] = cB[t]; }
  ldsS[t] = 0.f; ldsS[256 + t] = 0.f;

  int lane = t & 63, w = t >> 6;
  int or0 = (w >> 1)*64, c0w = (w & 1)*64;
  int lr = lane & 15, lg = lane >> 4;
  short8 af[4][4];
  #pragma unroll
  for (int ks = 0; ks < 4; ++ks)
    #pragma unroll
    for (int i = 0; i < 4; ++i)
      af[ks][i] = *(const short8*)(Wbf + (or0 + 16*i + lr)*128 + ks*32 + 8*lg);
  __syncthreads();

  // phase 1: load y, normalize+relu, bf16 -> LDS
  {
    int colL = t >> 1, half = t & 1;
    const unsigned short* src = ybuf + (size_t)(c0 + colL)*128 + half*64;
    int sc = swzc(colL);
    #pragma unroll
    for (int cc = 0; cc < 8; ++cc){
      int ch0 = half*64 + cc*8;
      short8 yv = *(const short8*)(src + cc*8);
      short8 xv;
      #pragma unroll
      for (int e = 0; e < 8; ++e){
        float f = bf2f((unsigned short)yv[e]);
        float v = fmaf(f, ldsA[ch0 + e], ldsB[ch0 + e]);
        v = v > 0.f ? v : 0.f;
        xv[e] = (short)f2bf(v);
      }
      *(short8*)(X + (ch0 >> 3)*1024 + sc*8) = xv;
    }
  }
  __syncthreads();

  // phase 2: MFMA
  f4 acc[4][4] = {};
  #pragma unroll
  for (int ks = 0; ks < 4; ++ks){
    short8 bfr[4];
    #pragma unroll
    for (int j = 0; j < 4; ++j)
      bfr[j] = *(const short8*)(X + (ks*4 + lg)*1024 + swzc(c0w + 16*j + lr)*8);
    #pragma unroll
    for (int i = 0; i < 4; ++i)
      #pragma unroll
      for (int j = 0; j < 4; ++j)
        acc[i][j] = __builtin_amdgcn_mfma_f32_16x16x32_bf16(af[ks][i], bfr[j], acc[i][j], 0, 0, 0);
  }

  // stats of raw output (deterministic: unique-writer LDS slots)
  #pragma unroll
  for (int i = 0; i < 4; ++i)
    #pragma unroll
    for (int e = 0; e < 4; ++e){
      float a0 = acc[i][0][e], a1 = acc[i][1][e], a2 = acc[i][2][e], a3 = acc[i][3][e];
      float s1 = (a0 + a1) + (a2 + a3);
      float s2 = (a0*a0 + a1*a1) + (a2*a2 + a3*a3);
      #pragma unroll
      for (int sft = 1; sft < 16; sft <<= 1){ s1 += __shfl_xor(s1, sft); s2 += __shfl_xor(s2, sft); }
      if (lr == 0){
        int o = or0 + 16*i + 4*lg + e;
        ldsS[(w & 1)*256 + o] = s1;
        ldsS[(w & 1)*256 + 128 + o] = s2;
      }
    }

  if (!LAST){
    __syncthreads();                          // all X reads done
    unsigned short* OT = (unsigned short*)lds; // [128 col][136] bf16
    #pragma unroll
    for (int i = 0; i < 4; ++i)
      #pragma unroll
      for (int j = 0; j < 4; ++j){
        int col = c0w + 16*j + lr;
        int o0 = or0 + 16*i + 4*lg;
        unsigned long long pv =
            (unsigned long long)f2bf(acc[i][j][0])
          | ((unsigned long long)f2bf(acc[i][j][1]) << 16)
          | ((unsigned long long)f2bf(acc[i][j][2]) << 32)
          | ((unsigned long long)f2bf(acc[i][j][3]) << 48);
        *(unsigned long long*)(OT + col*136 + o0) = pv;
      }
    __syncthreads();
    {
      int colL = t >> 1, half = t & 1;
      unsigned short* dst = ybuf + (size_t)(c0 + colL)*128 + half*64;
      #pragma unroll
      for (int cc = 0; cc < 8; ++cc){
        short8 v = *(const short8*)(OT + colL*136 + half*64 + cc*8);
        *(short8*)(dst + cc*8) = v;
      }
    }
    __syncthreads();
    partials[(size_t)blockIdx.x*256 + t] = ldsS[t] + ldsS[256 + t];
  } else {
    // max over 16 k's: each 16-lane lr-slice of a col-group is one point
    float keep[4][4] = {};
    #pragma unroll
    for (int j = 0; j < 4; ++j)
      #pragma unroll
      for (int i = 0; i < 4; ++i)
        #pragma unroll
        for (int e = 0; e < 4; ++e){
          float v = acc[i][j][e];
          #pragma unroll
          for (int sft = 1; sft < 16; sft <<= 1) v = fmaxf(v, __shfl_xor(v, sft));
          if (lr == j) keep[i][e] = v;
        }
    if (lr < 4){
      int colg = c0 + c0w + 16*lr;
      int nabs = colg >> 4;
      float* dst = y2max + (size_t)nabs*C_;
      #pragma unroll
      for (int i = 0; i < 4; ++i){
        f4 v; v.x = keep[i][0]; v.y = keep[i][1]; v.z = keep[i][2]; v.w = keep[i][3];
        *(f4*)(dst + or0 + 16*i + 4*lg) = v;
      }
    }
    __syncthreads();
    partials[(size_t)blockIdx.x*256 + t] = ldsS[t] + ldsS[256 + t];
  }
}

// ---------------------------------------------------------------------------
// K7: out[b][o][n] = relu(A2*y2max[b][n][o] + B2)   (LDS transpose)
// ---------------------------------------------------------------------------
__global__ __launch_bounds__(256) void k7_out(
    const float* __restrict__ y2max, const float* __restrict__ cA,
    const float* __restrict__ cB, float* __restrict__ outF)
{
  __shared__ __align__(16) float T[128*65];
  int t = threadIdx.x, bid = blockIdx.x;
  int b = bid >> 6, n0 = (bid & 63)*64;
  {
    int nl = t >> 2, o0 = (t & 3)*32;
    const float* src = y2max + ((size_t)b*N_ + n0 + nl)*C_ + o0;
    #pragma unroll
    for (int jj = 0; jj < 8; ++jj){
      f4 v = *(const f4*)(src + jj*4);
      T[(o0 + jj*4 + 0)*65 + nl] = v.x;
      T[(o0 + jj*4 + 1)*65 + nl] = v.y;
      T[(o0 + jj*4 + 2)*65 + nl] = v.z;
      T[(o0 + jj*4 + 3)*65 + nl] = v.w;
    }
  }
  __syncthreads();
  {
    int o = t >> 1, half = t & 1;
    float A = cA[o], Bb = cB[o];
    float* dst = outF + ((size_t)b*C_ + o)*N_ + n0 + half*32;
    #pragma unroll
    for (int jj = 0; jj < 8; ++jj){
      f4 v;
      float x0 = fmaf(T[o*65 + half*32 + jj*4+0], A, Bb);
      float x1 = fmaf(T[o*65 + half*32 + jj*4+1], A, Bb);
      float x2 = fmaf(T[o*65 + half*32 + jj*4+2], A, Bb);
      float x3 = fmaf(T[o*65 + half*32 + jj*4+3], A, Bb);
      v.x = x0 > 0.f ? x0 : 0.f; v.y = x1 > 0.f ? x1 : 0.f;
      v.z = x2 > 0.f ? x2 : 0.f; v.w = x3 > 0.f ? x3 : 0.f;
      *(f4*)(dst + jj*4) = v;
    }
  }
}

// ---------------------------------------------------------------------------
extern "C" void kernel_launch(void* const* d_in, const int* in_sizes, int n_in,
                              void* d_out, int out_size, void* d_ws, size_t ws_size,
                              hipStream_t stream)
{
  (void)in_sizes; (void)n_in; (void)out_size; (void)ws_size;
  const float* pos1  = (const float*)d_in[0];
  const float* pos2  = (const float*)d_in[1];
  const float* feat1 = (const float*)d_in[2];
  const float* feat2 = (const float*)d_in[3];
  const float* W0 = (const float*)d_in[4];
  const float* W1 = (const float*)d_in[5];
  const float* W2 = (const float*)d_in[6];
  const float* g0 = (const float*)d_in[7];
  const float* g1 = (const float*)d_in[8];
  const float* g2 = (const float*)d_in[9];
  const float* b0 = (const float*)d_in[10];
  const float* b1 = (const float*)d_in[11];
  const float* b2 = (const float*)d_in[12];

  char* ws = (char*)d_ws;
  size_t off = 0;
  auto alloc = [&](size_t bytes){ size_t r = off; off += (bytes + 255) & ~(size_t)255; return r; };
  float* knn_d   = (float*)(ws + alloc((size_t)NQ*64*4));          // 4 MB
  int*   knn_i   = (int*)  (ws + alloc((size_t)NQ*64*4));          // 4 MB
  int*   idx     = (int*)  (ws + alloc((size_t)COLS_TOT*4));       // 1 MB
  float* F2t     = (float*)(ws + alloc((size_t)NQ*C_*4));          // 8 MB
  float* PREt    = (float*)(ws + alloc((size_t)NQ*C_*4));          // 8 MB
  unsigned short* ybuf = (unsigned short*)(ws + alloc((size_t)COLS_TOT*C_*2)); // 64 MiB
  float* y2max   = (float*)(ws + alloc((size_t)NQ*C_*4));          // 8 MB
  float* partials= (float*)(ws + alloc((size_t)2048*256*4));       // 2 MB
  float* partial2= (float*)(ws + alloc((size_t)64*256*4));
  float* coef    = (float*)(ws + alloc((size_t)6*128*4));
  unsigned short* W0bb = (unsigned short*)(ws + alloc(16384*2));
  unsigned short* W0cb = (unsigned short*)(ws + alloc(16384*2));
  unsigned short* W1b  = (unsigned short*)(ws + alloc(16384*2));
  unsigned short* W2b  = (unsigned short*)(ws + alloc(16384*2));

  float* cA0 = coef,       *cB0 = coef + 128;
  float* cA1 = coef + 256, *cB1 = coef + 384;
  float* cA2 = coef + 512, *cB2 = coef + 640;

  wconv<<<256, 256, 0, stream>>>(W0, W1, W2, W0bb, W0cb, W1b, W2b);
  knn_chunk<<<256, 256, 0, stream>>>(pos1, pos2, knn_d, knn_i);
  knn_merge<<<64, 256, 0, stream>>>(knn_d, knn_i, idx);
  p1_gemm<<<256, 256, 0, stream>>>(feat2, feat1, W0bb, W0cb, F2t, PREt);
  k3_y0<<<1024, 256, 0, stream>>>(pos1, pos2, W0, idx, F2t, PREt, ybuf, partials);
  reduce1<<<32, 256, 0, stream>>>(partials, partial2);
  finalize<<<1, 256, 0, stream>>>(partial2, 32, g0, b0, cA0, cB0);
  layer_gemm<0><<<2048, 256, 0, stream>>>(ybuf, W1b, cA0, cB0, nullptr, partials);
  reduce1<<<64, 256, 0, stream>>>(partials, partial2);
  finalize<<<1, 256, 0, stream>>>(partial2, 64, g1, b1, cA1, cB1);
  layer_gemm<1><<<2048, 256, 0, stream>>>(ybuf, W2b, cA1, cB1, y2max, partials);
  reduce1<<<64, 256, 0, stream>>>(partials, partial2);
  finalize<<<1, 256, 0, stream>>>(partial2, 64, g2, b2, cA2, cB2);
  k7_out<<<256, 256, 0, stream>>>(y2max, cA2, cB2, (float*)d_out + (size_t)B_*3*N_);
  hipMemcpyAsync(d_out, d_in[0], (size_t)B_*3*N_*4, hipMemcpyDeviceToDevice, stream);
}

// Round 12
// 410.445 us; speedup vs baseline: 10.5509x; 1.0093x over previous
//
#include <hip/hip_runtime.h>

#define B_ 4
#define N_ 4096
#define K_ 16
#define C_ 128
#define NQ (B_*N_)            // 16384 query points
#define COLS_TOT (NQ*K_)      // 262144 (b,n,k) columns
#define CNT_F 262144.0f
#define EPS_ 1e-5f

typedef __attribute__((ext_vector_type(8))) short short8;
typedef __attribute__((ext_vector_type(4))) float f4;
typedef __attribute__((ext_vector_type(4))) int i4;

__device__ __forceinline__ unsigned short f2bf(float f){
  unsigned u = __builtin_bit_cast(unsigned, f);
  u = u + 0x7fffu + ((u >> 16) & 1u);     // RNE
  return (unsigned short)(u >> 16);
}
__device__ __forceinline__ float bf2f(unsigned short h){
  return __builtin_bit_cast(float, ((unsigned)h) << 16);
}
// LDS column swizzle: XOR low3 col bits with bits 3..5 -> spreads bank groups
__device__ __forceinline__ int swzc(int c){ return c ^ ((c >> 3) & 7); }

// ---------------------------------------------------------------------------
// Weight conversion: W0b=W0[:,3:131], W0c=W0[:,131:259], W1, W2 -> bf16
// ---------------------------------------------------------------------------
__global__ __launch_bounds__(256) void wconv(
    const float* __restrict__ W0, const float* __restrict__ W1, const float* __restrict__ W2,
    unsigned short* __restrict__ W0b, unsigned short* __restrict__ W0c,
    unsigned short* __restrict__ W1b, unsigned short* __restrict__ W2b)
{
  int i = blockIdx.x * 256 + threadIdx.x;     // 0..65535
  int sel = i >> 14, r = i & 16383;
  int o = r >> 7, c = r & 127;
  float v; unsigned short* dst;
  if (sel == 0)      { v = W0[o*259 + 3   + c]; dst = W0b; }
  else if (sel == 1) { v = W0[o*259 + 131 + c]; dst = W0c; }
  else if (sel == 2) { v = W1[o*128 + c];       dst = W1b; }
  else               { v = W2[o*128 + c];       dst = W2b; }
  dst[r] = f2bf(v);
}

// ---------------------------------------------------------------------------
// KNN stage 1 — sgemm-mirror fp32 arithmetic (VERIFIED r10):
//   sq  = rn(rn(rn(x*x)+rn(y*y))+rn(z*z))
//   dot = fma(z1,z2, fma(y1,y2, rn(x1*x2)))      (BLAS k-ascending FMA)
//   d   = rn(rn(sq1+sq2) - 2*dot)
// 16 chunks x 256 candidates -> grid 1024 (4 blocks/CU, 50% occupancy).
// Pending-buffer top-16, stable low-index ties.
// ---------------------------------------------------------------------------
__global__ __launch_bounds__(256) void knn_chunk(
    const float* __restrict__ pos1, const float* __restrict__ pos2,
    float* __restrict__ kdout, int* __restrict__ kiout)
{
  __shared__ __align__(16) float pts[256*4];    // 4 KB
  int bx = blockIdx.x;
  int b = bx >> 8, rest = bx & 255, ngrp = rest >> 4, chunk = rest & 15;
  int t = threadIdx.x;
  int m0 = chunk * 256;
  const float* p2 = pos2 + (size_t)b*3*N_;
  {
    int m = m0 + t;
    float x = p2[m], y = p2[N_ + m], z = p2[2*N_ + m];
    float sq = __fadd_rn(__fadd_rn(__fmul_rn(x,x), __fmul_rn(y,y)), __fmul_rn(z,z));
    f4 v; v.x = x; v.y = y; v.z = z; v.w = sq;
    *(f4*)(pts + t*4) = v;
  }
  __syncthreads();

  int n = ngrp*256 + t;
  const float* p1 = pos1 + (size_t)b*3*N_;
  float qx = p1[n], qy = p1[N_ + n], qz = p1[2*N_ + n];
  float qs = __fadd_rn(__fadd_rn(__fmul_rn(qx,qx), __fmul_rn(qy,qy)), __fmul_rn(qz,qz));

  float kd[16]; int ki[16];
  #pragma unroll
  for (int j = 0; j < 16; ++j){ kd[j] = 3.4e38f; ki[j] = 0; }
  float worst = 3.4e38f;
  float pd = 0.f; int pi = 0; bool pv = false;

  auto flush = [&](){
    float d0 = pv ? pd : 3.4e38f; int i0 = pi;
    #pragma unroll
    for (int j = 15; j >= 1; --j){
      bool cj = kd[j] > d0, cm = kd[j-1] > d0;
      kd[j] = cj ? (cm ? kd[j-1] : d0) : kd[j];
      ki[j] = cj ? (cm ? ki[j-1] : i0) : ki[j];
    }
    { bool c0 = kd[0] > d0; kd[0] = c0 ? d0 : kd[0]; ki[0] = c0 ? i0 : ki[0]; }
    worst = kd[15]; pv = false;
  };

  for (int bt = 0; bt < 32; ++bt){
    #pragma unroll
    for (int e = 0; e < 8; ++e){
      int it = bt*8 + e;
      f4 c = *(const f4*)(pts + it*4);
      float dot = __builtin_fmaf(qz, c.z,
                    __builtin_fmaf(qy, c.y, __fmul_rn(qx, c.x)));
      float d = __fsub_rn(__fadd_rn(qs, c.w), __fmul_rn(2.0f, dot));
      bool pass = d < worst;
      if (__any(pass && pv)) flush();     // overflow flush
      if (pass){ pd = d; pi = m0 + it; pv = true; }
    }
    if (__any(pv)) flush();
  }
  if (__any(pv)) flush();

  int q = b*N_ + n;
  #pragma unroll
  for (int j = 0; j < 16; ++j){
    kdout[(size_t)q*256 + chunk*16 + j] = kd[j];
    kiout[(size_t)q*256 + chunk*16 + j] = ki[j];
  }
}

// KNN stage 2: merge 16 sorted 16-lists (stable low-index: chunks in order).
// Early exit per list: sorted ascending + kd[15] nonincreasing => once an
// entry fails to insert, the rest of that list cannot.
__global__ __launch_bounds__(256) void knn_merge(
    const float* __restrict__ kdin, const int* __restrict__ kiin, int* __restrict__ idxout)
{
  int q = blockIdx.x*256 + threadIdx.x;
  float kd[16]; int ki[16];
  #pragma unroll
  for (int j = 0; j < 16; ++j){ kd[j] = 3.4e38f; ki[j] = 0; }
  const float* dsrc = kdin + (size_t)q*256;
  const int*   isrc = kiin + (size_t)q*256;
  for (int l = 0; l < 16; ++l){
    bool dead = false;
    #pragma unroll 1
    for (int s4 = 0; s4 < 4; ++s4){
      if (__all(dead)) break;
      f4 dv = *(const f4*)(dsrc + l*16 + s4*4);
      i4 iv = *(const i4*)(isrc + l*16 + s4*4);
      #pragma unroll
      for (int e = 0; e < 4; ++e){
        float d0 = dv[e]; int i0 = iv[e];
        bool ins = !dead && (kd[15] > d0);
        dead = dead || !ins;
        if (ins){
          #pragma unroll
          for (int j = 15; j >= 1; --j){
            bool cj = kd[j] > d0, cm = kd[j-1] > d0;
            kd[j] = cj ? (cm ? kd[j-1] : d0) : kd[j];
            ki[j] = cj ? (cm ? ki[j-1] : i0) : ki[j];
          }
          bool c0 = kd[0] > d0; kd[0] = c0 ? d0 : kd[0]; ki[0] = c0 ? i0 : ki[0];
        }
      }
    }
  }
  #pragma unroll
  for (int j = 0; j < 16; ++j) idxout[(size_t)q*16 + j] = ki[j];
}

// ---------------------------------------------------------------------------
// P1: F2t[b][m][o] = (W0b @ feature2), PREt[b][n][o] = (W0c @ feature1)
// ---------------------------------------------------------------------------
__global__ __launch_bounds__(256) void p1_gemm(
    const float* __restrict__ feat2, const float* __restrict__ feat1,
    const unsigned short* __restrict__ W0b, const unsigned short* __restrict__ W0c,
    float* __restrict__ F2t, float* __restrict__ PREt)
{
  __shared__ __align__(16) unsigned short X[16*128*8];  // 32KB
  int bid = blockIdx.x;
  int sel = bid >> 7;
  const float* src = sel ? feat1 : feat2;
  const unsigned short* W = sel ? W0c : W0b;
  float* dst = sel ? PREt : F2t;
  int c0 = (bid & 127) * 128;
  int b = c0 >> 12, mm0 = c0 & 4095;
  int t = threadIdx.x;
  {
    int ch = t >> 1, half = t & 1;
    const float* s = src + ((size_t)b*C_ + ch)*N_ + mm0 + half*64;
    int kb = ch >> 3, e = ch & 7;
    for (int mi = 0; mi < 64; ++mi){
      int col = half*64 + mi;
      X[kb*1024 + swzc(col)*8 + e] = f2bf(s[mi]);
    }
  }
  int lane = t & 63, w = t >> 6;
  int or0 = (w >> 1)*64, c0w = (w & 1)*64;
  int lr = lane & 15, lg = lane >> 4;
  short8 af[4][4];
  #pragma unroll
  for (int ks = 0; ks < 4; ++ks)
    #pragma unroll
    for (int i = 0; i < 4; ++i)
      af[ks][i] = *(const short8*)(W + (or0 + 16*i + lr)*128 + ks*32 + 8*lg);
  __syncthreads();

  f4 acc[4][4] = {};
  #pragma unroll
  for (int ks = 0; ks < 4; ++ks){
    short8 bfr[4];
    #pragma unroll
    for (int j = 0; j < 4; ++j)
      bfr[j] = *(const short8*)(X + (ks*4 + lg)*1024 + swzc(c0w + 16*j + lr)*8);
    #pragma unroll
    for (int i = 0; i < 4; ++i)
      #pragma unroll
      for (int j = 0; j < 4; ++j)
        acc[i][j] = __builtin_amdgcn_mfma_f32_16x16x32_bf16(af[ks][i], bfr[j], acc[i][j], 0, 0, 0);
  }
  #pragma unroll
  for (int i = 0; i < 4; ++i)
    #pragma unroll
    for (int j = 0; j < 4; ++j){
      int col = c0 + c0w + 16*j + lr;
      *(f4*)(dst + (size_t)col*C_ + or0 + 16*i + 4*lg) = acc[i][j];
    }
}

// ---------------------------------------------------------------------------
// K3: y0[col][o] = F2t[b][m][o] + PREt[b][n][o] + W0a . pos_diff  (raw, pre-BN)
// ---------------------------------------------------------------------------
__global__ __launch_bounds__(256) void k3_y0(
    const float* __restrict__ pos1, const float* __restrict__ pos2,
    const float* __restrict__ W0, const int* __restrict__ idx,
    const float* __restrict__ F2t, const float* __restrict__ PREt,
    unsigned short* __restrict__ ybuf, float* __restrict__ partials)
{
  __shared__ float w0a[384];
  __shared__ float ldsS[256];
  int t = threadIdx.x;
  for (int i = t; i < 384; i += 256) w0a[i] = W0[(i/3)*259 + (i%3)];
  __syncthreads();
  int cloc = t & 15, chg = t >> 4, ch0 = chg*8;
  float wx[8], wy[8], wz[8];
  #pragma unroll
  for (int e = 0; e < 8; ++e){
    wx[e] = w0a[(ch0+e)*3]; wy[e] = w0a[(ch0+e)*3+1]; wz[e] = w0a[(ch0+e)*3+2];
  }
  float s1[8] = {}, s2[8] = {};
  int base = blockIdx.x * 256;
  for (int it = 0; it < 16; ++it){
    int col = base + it*16 + cloc;
    int nabs = col >> 4;
    int b = nabs >> 12, n = nabs & 4095;
    int m = idx[col];
    float dx = pos2[(size_t)(b*3+0)*N_ + m] - pos1[(size_t)(b*3+0)*N_ + n];
    float dy = pos2[(size_t)(b*3+1)*N_ + m] - pos1[(size_t)(b*3+1)*N_ + n];
    float dz = pos2[(size_t)(b*3+2)*N_ + m] - pos1[(size_t)(b*3+2)*N_ + n];
    const float* f2 = F2t  + ((size_t)b*N_ + m)*C_ + ch0;
    const float* pr = PREt + ((size_t)b*N_ + n)*C_ + ch0;
    short8 sv;
    #pragma unroll
    for (int e = 0; e < 8; ++e){
      float y = f2[e] + pr[e];
      y = fmaf(wx[e], dx, y); y = fmaf(wy[e], dy, y); y = fmaf(wz[e], dz, y);
      s1[e] += y; s2[e] = fmaf(y, y, s2[e]);
      sv[e] = (short)f2bf(y);
    }
    *(short8*)(ybuf + (size_t)col*C_ + ch0) = sv;
  }
  #pragma unroll
  for (int e = 0; e < 8; ++e){
    float a = s1[e], q = s2[e];
    #pragma unroll
    for (int sft = 1; sft < 16; sft <<= 1){ a += __shfl_xor(a, sft); q += __shfl_xor(q, sft); }
    if (cloc == 0){ ldsS[ch0 + e] = a; ldsS[128 + ch0 + e] = q; }
  }
  __syncthreads();
  partials[(size_t)blockIdx.x*256 + t] = ldsS[t];
}

// ---------------------------------------------------------------------------
// Stats reduction (deterministic, 2 stages) + BN coef
// ---------------------------------------------------------------------------
__global__ __launch_bounds__(256) void reduce1(const float* __restrict__ partials,
                                               float* __restrict__ partial2)
{
  int t = threadIdx.x, r0 = blockIdx.x*32;
  float a = 0.f;
  #pragma unroll 4
  for (int i = 0; i < 32; ++i) a += partials[(size_t)(r0+i)*256 + t];
  partial2[(size_t)blockIdx.x*256 + t] = a;
}

__global__ __launch_bounds__(256) void finalize(const float* __restrict__ partial2, int rows,
    const float* __restrict__ g, const float* __restrict__ bb,
    float* __restrict__ cA, float* __restrict__ cB)
{
  __shared__ float sh[256];
  int t = threadIdx.x;
  float a = 0.f;
  for (int i = 0; i < rows; ++i) a += partial2[(size_t)i*256 + t];
  sh[t] = a;
  __syncthreads();
  if (t < 128){
    float mu = sh[t] / CNT_F;
    float var = sh[128 + t] / CNT_F - mu*mu;
    float A = g[t] * rsqrtf(var + EPS_);
    cA[t] = A; cB[t] = bb[t] - mu*A;
  }
}

// ---------------------------------------------------------------------------
// Layer GEMM: x = relu(A*y_in+B) (bf16), y_out = W @ x. In-place on ybuf.
// LAST=1: max-reduce over K in-register, store y2max.
// ---------------------------------------------------------------------------
template<int LAST>
__global__ __launch_bounds__(256,2) void layer_gemm(
    unsigned short* ybuf,
    const unsigned short* __restrict__ Wbf,
    const float* __restrict__ cA, const float* __restrict__ cB,
    float* __restrict__ y2max,
    float* __restrict__ partials)
{
  __shared__ __align__(16) char lds[38912];
  unsigned short* X = (unsigned short*)lds;      // 32KB
  float* ldsA = (float*)(lds + 34816);
  float* ldsB = ldsA + 128;
  float* ldsS = ldsB + 128;                      // [2][256]
  int t = threadIdx.x;
  int c0 = blockIdx.x * 128;
  if (t < 128){ ldsA[t] = cA[t]; ldsB[t] = cB[t]; }
  ldsS[t] = 0.f; ldsS[256 + t] = 0.f;

  int lane = t & 63, w = t >> 6;
  int or0 = (w >> 1)*64, c0w = (w & 1)*64;
  int lr = lane & 15, lg = lane >> 4;
  short8 af[4][4];
  #pragma unroll
  for (int ks = 0; ks < 4; ++ks)
    #pragma unroll
    for (int i = 0; i < 4; ++i)
      af[ks][i] = *(const short8*)(Wbf + (or0 + 16*i + lr)*128 + ks*32 + 8*lg);
  __syncthreads();

  {
    int colL = t >> 1, half = t & 1;
    const unsigned short* src = ybuf + (size_t)(c0 + colL)*128 + half*64;
    int sc = swzc(colL);
    #pragma unroll
    for (int cc = 0; cc < 8; ++cc){
      int ch0 = half*64 + cc*8;
      short8 yv = *(const short8*)(src + cc*8);
      short8 xv;
      #pragma unroll
      for (int e = 0; e < 8; ++e){
        float f = bf2f((unsigned short)yv[e]);
        float v = fmaf(f, ldsA[ch0 + e], ldsB[ch0 + e]);
        v = v > 0.f ? v : 0.f;
        xv[e] = (short)f2bf(v);
      }
      *(short8*)(X + (ch0 >> 3)*1024 + sc*8) = xv;
    }
  }
  __syncthreads();

  f4 acc[4][4] = {};
  #pragma unroll
  for (int ks = 0; ks < 4; ++ks){
    short8 bfr[4];
    #pragma unroll
    for (int j = 0; j < 4; ++j)
      bfr[j] = *(const short8*)(X + (ks*4 + lg)*1024 + swzc(c0w + 16*j + lr)*8);
    #pragma unroll
    for (int i = 0; i < 4; ++i)
      #pragma unroll
      for (int j = 0; j < 4; ++j)
        acc[i][j] = __builtin_amdgcn_mfma_f32_16x16x32_bf16(af[ks][i], bfr[j], acc[i][j], 0, 0, 0);
  }

  #pragma unroll
  for (int i = 0; i < 4; ++i)
    #pragma unroll
    for (int e = 0; e < 4; ++e){
      float a0 = acc[i][0][e], a1 = acc[i][1][e], a2 = acc[i][2][e], a3 = acc[i][3][e];
      float s1 = (a0 + a1) + (a2 + a3);
      float s2 = (a0*a0 + a1*a1) + (a2*a2 + a3*a3);
      #pragma unroll
      for (int sft = 1; sft < 16; sft <<= 1){ s1 += __shfl_xor(s1, sft); s2 += __shfl_xor(s2, sft); }
      if (lr == 0){
        int o = or0 + 16*i + 4*lg + e;
        ldsS[(w & 1)*256 + o] = s1;
        ldsS[(w & 1)*256 + 128 + o] = s2;
      }
    }

  if (!LAST){
    __syncthreads();
    unsigned short* OT = (unsigned short*)lds; // [128 col][136] bf16
    #pragma unroll
    for (int i = 0; i < 4; ++i)
      #pragma unroll
      for (int j = 0; j < 4; ++j){
        int col = c0w + 16*j + lr;
        int o0 = or0 + 16*i + 4*lg;
        unsigned long long pv =
            (unsigned long long)f2bf(acc[i][j][0])
          | ((unsigned long long)f2bf(acc[i][j][1]) << 16)
          | ((unsigned long long)f2bf(acc[i][j][2]) << 32)
          | ((unsigned long long)f2bf(acc[i][j][3]) << 48);
        *(unsigned long long*)(OT + col*136 + o0) = pv;
      }
    __syncthreads();
    {
      int colL = t >> 1, half = t & 1;
      unsigned short* dst = ybuf + (size_t)(c0 + colL)*128 + half*64;
      #pragma unroll
      for (int cc = 0; cc < 8; ++cc){
        short8 v = *(const short8*)(OT + colL*136 + half*64 + cc*8);
        *(short8*)(dst + cc*8) = v;
      }
    }
    __syncthreads();
    partials[(size_t)blockIdx.x*256 + t] = ldsS[t] + ldsS[256 + t];
  } else {
    float keep[4][4] = {};
    #pragma unroll
    for (int j = 0; j < 4; ++j)
      #pragma unroll
      for (int i = 0; i < 4; ++i)
        #pragma unroll
        for (int e = 0; e < 4; ++e){
          float v = acc[i][j][e];
          #pragma unroll
          for (int sft = 1; sft < 16; sft <<= 1) v = fmaxf(v, __shfl_xor(v, sft));
          if (lr == j) keep[i][e] = v;
        }
    if (lr < 4){
      int colg = c0 + c0w + 16*lr;
      int nabs = colg >> 4;
      float* dst = y2max + (size_t)nabs*C_;
      #pragma unroll
      for (int i = 0; i < 4; ++i){
        f4 v; v.x = keep[i][0]; v.y = keep[i][1]; v.z = keep[i][2]; v.w = keep[i][3];
        *(f4*)(dst + or0 + 16*i + 4*lg) = v;
      }
    }
    __syncthreads();
    partials[(size_t)blockIdx.x*256 + t] = ldsS[t] + ldsS[256 + t];
  }
}

// ---------------------------------------------------------------------------
// K7: out[b][o][n] = relu(A2*y2max[b][n][o] + B2)   (LDS transpose)
// ---------------------------------------------------------------------------
__global__ __launch_bounds__(256) void k7_out(
    const float* __restrict__ y2max, const float* __restrict__ cA,
    const float* __restrict__ cB, float* __restrict__ outF)
{
  __shared__ __align__(16) float T[128*65];
  int t = threadIdx.x, bid = blockIdx.x;
  int b = bid >> 6, n0 = (bid & 63)*64;
  {
    int nl = t >> 2, o0 = (t & 3)*32;
    const float* src = y2max + ((size_t)b*N_ + n0 + nl)*C_ + o0;
    #pragma unroll
    for (int jj = 0; jj < 8; ++jj){
      f4 v = *(const f4*)(src + jj*4);
      T[(o0 + jj*4 + 0)*65 + nl] = v.x;
      T[(o0 + jj*4 + 1)*65 + nl] = v.y;
      T[(o0 + jj*4 + 2)*65 + nl] = v.z;
      T[(o0 + jj*4 + 3)*65 + nl] = v.w;
    }
  }
  __syncthreads();
  {
    int o = t >> 1, half = t & 1;
    float A = cA[o], Bb = cB[o];
    float* dst = outF + ((size_t)b*C_ + o)*N_ + n0 + half*32;
    #pragma unroll
    for (int jj = 0; jj < 8; ++jj){
      f4 v;
      float x0 = fmaf(T[o*65 + half*32 + jj*4+0], A, Bb);
      float x1 = fmaf(T[o*65 + half*32 + jj*4+1], A, Bb);
      float x2 = fmaf(T[o*65 + half*32 + jj*4+2], A, Bb);
      float x3 = fmaf(T[o*65 + half*32 + jj*4+3], A, Bb);
      v.x = x0 > 0.f ? x0 : 0.f; v.y = x1 > 0.f ? x1 : 0.f;
      v.z = x2 > 0.f ? x2 : 0.f; v.w = x3 > 0.f ? x3 : 0.f;
      *(f4*)(dst + jj*4) = v;
    }
  }
}

// ---------------------------------------------------------------------------
extern "C" void kernel_launch(void* const* d_in, const int* in_sizes, int n_in,
                              void* d_out, int out_size, void* d_ws, size_t ws_size,
                              hipStream_t stream)
{
  (void)in_sizes; (void)n_in; (void)out_size; (void)ws_size;
  const float* pos1  = (const float*)d_in[0];
  const float* pos2  = (const float*)d_in[1];
  const float* feat1 = (const float*)d_in[2];
  const float* feat2 = (const float*)d_in[3];
  const float* W0 = (const float*)d_in[4];
  const float* W1 = (const float*)d_in[5];
  const float* W2 = (const float*)d_in[6];
  const float* g0 = (const float*)d_in[7];
  const float* g1 = (const float*)d_in[8];
  const float* g2 = (const float*)d_in[9];
  const float* b0 = (const float*)d_in[10];
  const float* b1 = (const float*)d_in[11];
  const float* b2 = (const float*)d_in[12];

  char* ws = (char*)d_ws;
  size_t off = 0;
  auto alloc = [&](size_t bytes){ size_t r = off; off += (bytes + 255) & ~(size_t)255; return r; };
  int*   idx     = (int*)  (ws + alloc((size_t)COLS_TOT*4));       // 1 MB
  float* F2t     = (float*)(ws + alloc((size_t)NQ*C_*4));          // 8 MB
  float* PREt    = (float*)(ws + alloc((size_t)NQ*C_*4));          // 8 MB
  unsigned short* ybuf = (unsigned short*)(ws + alloc((size_t)COLS_TOT*C_*2)); // 64 MiB
  float* y2max   = (float*)(ws + alloc((size_t)NQ*C_*4));          // 8 MB
  float* partials= (float*)(ws + alloc((size_t)2048*256*4));       // 2 MB
  float* partial2= (float*)(ws + alloc((size_t)64*256*4));
  float* coef    = (float*)(ws + alloc((size_t)6*128*4));
  unsigned short* W0bb = (unsigned short*)(ws + alloc(16384*2));
  unsigned short* W0cb = (unsigned short*)(ws + alloc(16384*2));
  unsigned short* W1b  = (unsigned short*)(ws + alloc(16384*2));
  unsigned short* W2b  = (unsigned short*)(ws + alloc(16384*2));

  // KNN scratch ALIASES ybuf (dead until k3_y0, consumed by knn_merge first):
  float* knn_d = (float*)ybuf;                                 // 16.8 MB
  int*   knn_i = (int*)((char*)ybuf + (size_t)NQ*256*4);       // 16.8 MB

  float* cA0 = coef,       *cB0 = coef + 128;
  float* cA1 = coef + 256, *cB1 = coef + 384;
  float* cA2 = coef + 512, *cB2 = coef + 640;

  wconv<<<256, 256, 0, stream>>>(W0, W1, W2, W0bb, W0cb, W1b, W2b);
  knn_chunk<<<1024, 256, 0, stream>>>(pos1, pos2, knn_d, knn_i);
  knn_merge<<<64, 256, 0, stream>>>(knn_d, knn_i, idx);
  p1_gemm<<<256, 256, 0, stream>>>(feat2, feat1, W0bb, W0cb, F2t, PREt);
  k3_y0<<<1024, 256, 0, stream>>>(pos1, pos2, W0, idx, F2t, PREt, ybuf, partials);
  reduce1<<<32, 256, 0, stream>>>(partials, partial2);
  finalize<<<1, 256, 0, stream>>>(partial2, 32, g0, b0, cA0, cB0);
  layer_gemm<0><<<2048, 256, 0, stream>>>(ybuf, W1b, cA0, cB0, nullptr, partials);
  reduce1<<<64, 256, 0, stream>>>(partials, partial2);
  finalize<<<1, 256, 0, stream>>>(partial2, 64, g1, b1, cA1, cB1);
  layer_gemm<1><<<2048, 256, 0, stream>>>(ybuf, W2b, cA1, cB1, y2max, partials);
  reduce1<<<64, 256, 0, stream>>>(partials, partial2);
  finalize<<<1, 256, 0, stream>>>(partial2, 64, g2, b2, cA2, cB2);
  k7_out<<<256, 256, 0, stream>>>(y2max, cA2, cB2, (float*)d_out + (size_t)B_*3*N_);
  hipMemcpyAsync(d_out, d_in[0], (size_t)B_*3*N_*4, hipMemcpyDeviceToDevice, stream);
}